// Round 5
// baseline (157.071 us; speedup 1.0000x reference)
//
#include <hip/hip_runtime.h>
#include <math.h>

#define NB 50
#define KA 4

__device__ __forceinline__ float dev_rmax() {
    // matches Python: float(2.0 * sqrt(1.0 / (2.0 * sqrt(3.0) * 1024))), folded in double
    return (float)(2.0 * sqrt(1.0 / (2.0 * sqrt(3.0) * 1024.0)));
}

// Single fused kernel, nblk = ceil(na/KA) blocks of 256 threads.
// Worker phase (all blocks): KA a-disks vs all b-disks; ballot-compact close
//   pairs (dist < 7.5, ~0.5%) into per-a LDS lists; wave w owns a-disk A0+w,
//   lane = bin for the exp + perimeter-weight epilogue; write dens bin-major.
// Finish: all threads release-fence, tid0 takes a ticket (device-scope
//   atomicAdd). The block drawing the LAST ticket acquire-fences and does the
//   50-bin mean/min/max reduction. No spin-waits anywhere: deadlock-free under
//   any scheduling. Ticket init is the harness's deterministic 0xAA poison of
//   d_ws (0xAAAAAAAA); a zeroed init is also accepted for the first call.
__global__ void __launch_bounds__(256)
pcf_fused(const float* __restrict__ da, const float* __restrict__ db,
          const int* __restrict__ scp, float* __restrict__ dens,
          unsigned int* __restrict__ ticket, float* __restrict__ out,
          int na, int nb, int nblk)
{
    const float RMAX = dev_rmax();
    const float PI = 3.14159265358979323846f;
    const float inv_rmax = 1.0f / RMAX;
    const int tid  = threadIdx.x;
    const int lane = tid & 63;
    const int wave = tid >> 6;
    const int sc   = scp[0];
    const int A0   = blockIdx.x * KA;

    __shared__ float list[KA][1024];   // worst-case capacity (all nb close)
    __shared__ int   cnt[KA];
    __shared__ int   amLastSh;

    float ax[KA], ay[KA], ar[KA];
#pragma unroll
    for (int aa = 0; aa < KA; ++aa) {
        const int ia = (A0 + aa < na) ? (A0 + aa) : (na - 1);
        ax[aa] = da[3*ia+0]; ay[aa] = da[3*ia+1]; ar[aa] = da[3*ia+2];
    }
    if (tid < KA) cnt[tid] = 0;
    __syncthreads();

    for (int base = 0; base < nb; base += 256) {
        const int j = base + tid;
        const bool jvalid = (j < nb);
        float bx = 0.0f, by = 0.0f, br = 0.0f;
        if (jvalid) { bx = db[3*j+0]; by = db[3*j+1]; br = db[3*j+2]; }
#pragma unroll
        for (int aa = 0; aa < KA; ++aa) {
            const float dx = ax[aa] - bx;
            const float dy = ay[aa] - by;
            const float d  = sqrtf(dx*dx + dy*dy);
            const float r1 = fmaxf(ar[aa], br);
            const float r2 = fminf(ar[aa], br);
            const float extent  = fmaxf(d + r1 + r2, 2.0f*r1);
            const float overlap = fmaxf(r1 + r2 - d, 0.0f);
            const float dist = (extent - overlap + d + r1 - r2) * inv_rmax;
            // exp(-16 x^2) underflows (f32) for |x|>2.55; bins span [0.1,5.0] ->
            // dist>=7.5 contributes < 1e-42 to any output. Safe to drop.
            const bool close = jvalid && (dist < 7.5f)
                               && !((sc != 0) && (j == A0 + aa));
            const unsigned long long m = __ballot(close);
            int wb = 0;
            if (lane == 0 && m) wb = atomicAdd(&cnt[aa], __popcll(m));
            wb = __shfl(wb, 0);
            if (close) list[aa][wb + __popcll(m & ((1ull << lane) - 1ull))] = dist;
        }
    }
    __syncthreads();

    // exp phase: wave w -> a-disk A0+w; lane = bin (lanes >= NB masked at store)
    const float binf = 0.1f * (float)(lane + 1);
    float acc = 0.0f;
    const int M = cnt[wave];
    for (int k = 0; k < M; ++k) {
        const float x = binf - list[wave][k];   // LDS broadcast read
        acc += __expf(-16.0f * x * x);
    }

    if (lane < NB && (A0 + wave) < na) {
        const int ia = A0 + wave;
        const float axw = da[3*ia+0];   // L1-hot reload (avoids dyn reg indexing)
        const float ayw = da[3*ia+1];
        const float GF = 1.0f / (sqrtf(PI) * 0.25f);   // 1/(sqrt(pi)*SIGMA)
        const float rs = 0.1f * (float)(lane + 1) * RMAX;

        // perimeter weight for (disk ia, bin lane)
        float full = 2.0f * PI;
        const float ex[4] = { axw, 1.0f - axw, ayw, 1.0f - ayw };
        const float ey[4] = { ayw, ayw,        axw, axw        };
#pragma unroll
        for (int c = 0; c < 4; ++c) {
            if (rs > ex[c]) {
                float ratio = ex[c] / rs;
                ratio = fminf(fmaxf(ratio, -1.0f), 1.0f);
                const float alpha = acosf(ratio);
                const float a1 = atan2f(ey[c], ex[c]);
                const float a2 = atan2f(1.0f - ey[c], ex[c]);
                full -= fminf(alpha, a1) + fminf(alpha, a2);
            }
        }
        float peri = full * (1.0f / (2.0f * PI));
        peri = fminf(fmaxf(peri, 0.0f), 1.0f);
        const float w = (peri > 0.0f) ? (1.0f / peri) : 0.0f;

        const float r_out = rs + 0.5f * RMAX;
        const float r_in  = fmaxf(rs - 0.5f * RMAX, 0.0f);
        const float area  = PI * (r_out * r_out - r_in * r_in);

        const float density = (GF * acc) * w / area / (float)nb;
        dens[lane * na + ia] = density;   // bin-major: reducer reads coalesced
    }

    // ---- last-block-done handoff (no spinning) ----
    __threadfence();                      // release: all this block's dens stores
    __syncthreads();
    if (tid == 0) {
        const unsigned int old = atomicAdd(ticket, 1u);   // device scope
        amLastSh = (old == 0xAAAAAAAAu + (unsigned int)(nblk - 1)) ||
                   (old == (unsigned int)(nblk - 1));
    }
    __syncthreads();
    if (!amLastSh) return;

    __threadfence();                      // acquire: see all blocks' dens stores
    __syncthreads();

    // wave w reduces bins w, w+4, ... : mean / min / max over na disks
    for (int b = wave; b < NB; b += 4) {
        float s = 0.0f, mn = INFINITY, mx = -INFINITY;
        for (int i = lane; i < na; i += 64) {
            const float v = dens[b * na + i];   // coalesced
            s += v; mn = fminf(mn, v); mx = fmaxf(mx, v);
        }
#pragma unroll
        for (int off = 32; off >= 1; off >>= 1) {
            s  += __shfl_down(s, off);
            mn  = fminf(mn, __shfl_down(mn, off));
            mx  = fmaxf(mx, __shfl_down(mx, off));
        }
        if (lane == 0) {
            const float rs = 0.1f * (float)(b + 1) * RMAX;
            out[2*b + 0] = rs / RMAX;       // pcf[:,0]
            out[2*b + 1] = s / (float)na;   // pcf[:,1] = mean
            out[100 + b] = mn;              // pcf_lower
            out[150 + b] = mx;              // pcf_upper
        }
    }
}

extern "C" void kernel_launch(void* const* d_in, const int* in_sizes, int n_in,
                              void* d_out, int out_size, void* d_ws, size_t ws_size,
                              hipStream_t stream)
{
    const float* da = (const float*)d_in[0];
    const float* db = (const float*)d_in[1];
    const int*   sc = (const int*)d_in[2];
    float* out  = (float*)d_out;
    float* dens = (float*)d_ws;                 // [NB][na] floats = 200 KB
    const int na = in_sizes[0] / 3;
    const int nb = in_sizes[1] / 3;
    const int nblk = (na + KA - 1) / KA;
    unsigned int* ticket =
        (unsigned int*)((char*)d_ws + (size_t)NB * na * sizeof(float));

    pcf_fused<<<nblk, 256, 0, stream>>>(da, db, sc, dens, ticket, out, na, nb, nblk);
}

// Round 6
// 63.434 us; speedup vs baseline: 2.4761x; 2.4761x over previous
//
#include <hip/hip_runtime.h>
#include <math.h>

#define NB 50

__device__ __forceinline__ float dev_rmax() {
    // matches Python: float(2.0 * sqrt(1.0 / (2.0 * sqrt(3.0) * 1024))), folded in double
    return (float)(2.0 * sqrt(1.0 / (2.0 * sqrt(3.0) * 1024.0)));
}

// One block (256 threads = 4 waves) per a-disk.
// Phase 1 per 256-j round: all threads compute disk distance, ballot-compact the
// close ones (dist < 7.5, ~0.5%) into an LDS list.
// Phase 2: lane = bin; each wave walks its strided share of the list, 1 exp per
// (entry, bin). Heavy exp work scales with ACTUAL close pairs.
// NOTE (R5 post-mortem): do NOT fuse the reduction into this dispatch. Device-
// scope fences (L2 writeback/inv per block) cost ~105 us on 8-XCD gfx950; the
// kernel boundary provides the same coherence for ~2 us.
__global__ void __launch_bounds__(256)
pcf_density_kernel(const float* __restrict__ da, const float* __restrict__ db,
                   const int* __restrict__ scp, float* __restrict__ dens,
                   int na, int nb)
{
    const float RMAX = dev_rmax();
    const float inv_rmax = 1.0f / RMAX;
    const int i    = blockIdx.x;
    const int tid  = threadIdx.x;
    const int lane = tid & 63;
    const int wave = tid >> 6;
    const int sc   = scp[0];

    __shared__ float list[256];     // per-round close-dist list (capped by round size)
    __shared__ int   cnt;
    __shared__ float part[4 * NB];  // per-wave partial bin sums

    if (tid == 0) cnt = 0;
    __syncthreads();

    // a-disk is block-uniform -> scalar loads
    const float ax = da[3*i+0];
    const float ay = da[3*i+1];
    const float ar = da[3*i+2];

    const float binf = 0.1f * (float)(lane + 1);  // rs/RMAX for bin=lane
    float accb = 0.0f;

    for (int base = 0; base < nb; base += 256) {
        const int j = base + tid;
        bool close = false;
        float dist = 0.0f;
        if (j < nb) {
            const float bx = db[3*j+0];
            const float by = db[3*j+1];
            const float br = db[3*j+2];
            const float dx = ax - bx;
            const float dy = ay - by;
            const float d  = sqrtf(dx*dx + dy*dy);
            const float r1 = fmaxf(ar, br);
            const float r2 = fminf(ar, br);
            const float extent  = fmaxf(d + r1 + r2, 2.0f*r1);
            const float overlap = fmaxf(r1 + r2 - d, 0.0f);
            dist = (extent - overlap + d + r1 - r2) * inv_rmax;
            // exp(-16 x^2) underflows (f32) for |x|>2.55; bins span [0.1,5.0] ->
            // dist>=7.5 contributes < 1e-42 to any output. Safe to drop.
            close = (dist < 7.5f) && !((sc != 0) && (j == i));
        }
        // wave-level ballot compaction into the block list
        const unsigned long long m = __ballot(close);
        const int total  = __popcll(m);
        const int prefix = __popcll(m & ((1ull << lane) - 1ull));
        int wbase = 0;
        if (lane == 0) wbase = atomicAdd(&cnt, total);
        wbase = __shfl(wbase, 0);
        if (close) list[wbase + prefix] = dist;
        __syncthreads();

        // lane = bin; waves stride over the compacted list
        const int M = cnt;
        for (int k = wave; k < M; k += 4) {
            const float dl = list[k];          // broadcast read, conflict-free
            const float x  = binf - dl;
            accb += __expf(-16.0f * x * x);
        }
        __syncthreads();
        if (tid == 0) cnt = 0;
        __syncthreads();
    }

    if (lane < NB) part[wave * NB + lane] = accb;
    __syncthreads();

    if (wave == 0 && lane < NB) {
        const float s = part[lane] + part[NB + lane] + part[2*NB + lane] + part[3*NB + lane];

        const float PI = 3.14159265358979323846f;
        const float GF = 1.0f / (sqrtf(PI) * 0.25f);   // 1/(sqrt(pi)*SIGMA)
        const float rs = 0.1f * (float)(lane + 1) * RMAX;

        // perimeter weight for (disk i, bin lane)
        float full = 2.0f * PI;
        const float ex[4] = { ax, 1.0f - ax, ay, 1.0f - ay };
        const float ey[4] = { ay, ay,        ax, ax        };
#pragma unroll
        for (int c = 0; c < 4; ++c) {
            if (rs > ex[c]) {
                float ratio = ex[c] / rs;
                ratio = fminf(fmaxf(ratio, -1.0f), 1.0f);
                const float alpha = acosf(ratio);
                const float a1 = atan2f(ey[c], ex[c]);
                const float a2 = atan2f(1.0f - ey[c], ex[c]);
                full -= fminf(alpha, a1) + fminf(alpha, a2);
            }
        }
        float peri = full * (1.0f / (2.0f * PI));
        peri = fminf(fmaxf(peri, 0.0f), 1.0f);
        const float w = (peri > 0.0f) ? (1.0f / peri) : 0.0f;

        const float r_out = rs + 0.5f * RMAX;
        const float r_in  = fmaxf(rs - 0.5f * RMAX, 0.0f);
        const float area  = PI * (r_out * r_out - r_in * r_in);

        const float density = (GF * s) * w / area / (float)nb;
        dens[lane * na + i] = density;   // bin-major for coalesced reduction
    }
}

// One block (256 threads) per bin: mean / min / max over the na a-disks.
__global__ void __launch_bounds__(256)
pcf_reduce_kernel(const float* __restrict__ dens, float* __restrict__ out, int na)
{
    const int b    = blockIdx.x;
    const int tid  = threadIdx.x;
    const int lane = tid & 63;
    const int wave = tid >> 6;
    const float RMAX = dev_rmax();

    __shared__ float rs_[4], rmn[4], rmx[4];

    float s = 0.0f, mn = INFINITY, mx = -INFINITY;
    for (int i = tid; i < na; i += 256) {
        const float v = dens[b * na + i];
        s  += v;
        mn  = fminf(mn, v);
        mx  = fmaxf(mx, v);
    }
#pragma unroll
    for (int off = 32; off >= 1; off >>= 1) {
        s  += __shfl_down(s, off);
        mn  = fminf(mn, __shfl_down(mn, off));
        mx  = fmaxf(mx, __shfl_down(mx, off));
    }
    if (lane == 0) { rs_[wave] = s; rmn[wave] = mn; rmx[wave] = mx; }
    __syncthreads();
    if (tid == 0) {
        float ts = rs_[0] + rs_[1] + rs_[2] + rs_[3];
        float tmn = fminf(fminf(rmn[0], rmn[1]), fminf(rmn[2], rmn[3]));
        float tmx = fmaxf(fmaxf(rmx[0], rmx[1]), fmaxf(rmx[2], rmx[3]));
        const float rs = 0.1f * (float)(b + 1) * RMAX;
        out[2*b + 0] = rs / RMAX;       // pcf[:,0]
        out[2*b + 1] = ts / (float)na;  // pcf[:,1] = mean
        out[100 + b] = tmn;             // pcf_lower
        out[150 + b] = tmx;             // pcf_upper
    }
}

extern "C" void kernel_launch(void* const* d_in, const int* in_sizes, int n_in,
                              void* d_out, int out_size, void* d_ws, size_t ws_size,
                              hipStream_t stream)
{
    const float* da = (const float*)d_in[0];
    const float* db = (const float*)d_in[1];
    const int*   sc = (const int*)d_in[2];
    float* out  = (float*)d_out;
    float* dens = (float*)d_ws;            // [NB][na] floats = 200 KB for na=1024
    const int na = in_sizes[0] / 3;
    const int nb = in_sizes[1] / 3;

    pcf_density_kernel<<<na, 256, 0, stream>>>(da, db, sc, dens, na, nb);
    pcf_reduce_kernel<<<NB, 256, 0, stream>>>(dens, out, na);
}